// Round 1
// baseline (376.314 us; speedup 1.0000x reference)
//
#include <hip/hip_runtime.h>

#define SZ 8192
#define WT_BYTES ((size_t)128 * 16384 * 2)   // 4 MB of bf16 transposed weights

typedef short short8 __attribute__((ext_vector_type(8)));
typedef float f32x4 __attribute__((ext_vector_type(4)));

static __device__ __forceinline__ unsigned short f2bf(float f){
    unsigned u = __float_as_uint(f);
    u += 0x7fffu + ((u >> 16) & 1u);          // RNE
    return (unsigned short)(u >> 16);
}

// ================= fast path (needs ws_size >= 4MB) =================
__global__ __launch_bounds__(256) void Monarch_prep(const float* __restrict__ w1,
                                                    const float* __restrict__ w2,
                                                    unsigned short* __restrict__ wt)
{
    __shared__ unsigned short T[128][132];
    int blk = blockIdx.x;
    const float* src = (blk < 64) ? (w1 + (size_t)blk * 16384)
                                  : (w2 + (size_t)(blk - 64) * 16384);
    unsigned short* dst = wt + (size_t)blk * 16384;
    int i  = threadIdx.x;
    int cs = i >> 5;
    int p0 = (i & 31) * 4;
    for (int rr = 0; rr < 16; ++rr){
        int c = rr * 8 + cs;
        f32x4 v = *(const f32x4*)(src + c * 128 + p0);
        T[p0 + 0][c] = f2bf(v[0]);
        T[p0 + 1][c] = f2bf(v[1]);
        T[p0 + 2][c] = f2bf(v[2]);
        T[p0 + 3][c] = f2bf(v[3]);
    }
    __syncthreads();
    for (int rr = 0; rr < 16; ++rr){
        int d = rr * 8 + cs;
        ushort4 o;
        o.x = T[d][p0 + 0]; o.y = T[d][p0 + 1]; o.z = T[d][p0 + 2]; o.w = T[d][p0 + 3];
        *(ushort4*)(dst + d * 128 + p0) = o;
    }
}

// 512 threads (8 waves) per block, 64 KB LDS -> 2 blocks/CU = 16 waves/CU (was 8).
// XCD-bijective remap: the 4 g-blocks sharing one x-tile land on the SAME XCD's L2.
__global__ __launch_bounds__(512, 4) void Monarch_main(const float* __restrict__ x,
                                                       const unsigned short* __restrict__ w1T,
                                                       const unsigned short* __restrict__ w2T,
                                                       const float* __restrict__ bias,
                                                       float* __restrict__ out)
{
    __shared__ __align__(16) unsigned short s[16 * 2048];

    int b     = blockIdx.x;
    int xcd   = b & 7;            // dispatch round-robins XCDs
    int local = b >> 3;
    int g     = local & 3;        // 4 consecutive locals (same XCD) share a tile
    int tile  = (xcd << 5) | (local >> 2);
    int t0    = tile << 4;
    int k0    = g << 4;
    int d0    = g << 5;

    int tid = threadIdx.x;
    int w   = tid >> 6;           // 0..7
    int l   = tid & 63;
    int m   = l & 15;
    int q   = l >> 4;

    // ---------- stage 1: h1 slice (16 rows x [d0,d0+32) x all 64 j-blocks) ----------
    const float* xrow = x + (size_t)(t0 + m) * SZ + q * 8;
    for (int jt = 0; jt < 8; ++jt){
        int j = (jt << 3) | w;
        f32x4 acc0 = {0.f, 0.f, 0.f, 0.f};
        f32x4 acc1 = {0.f, 0.f, 0.f, 0.f};
        const float* xp = xrow + j * 128;
        const unsigned short* w1p = w1T + ((size_t)(j * 128 + d0 + m)) * 128 + q * 8;
        #pragma unroll
        for (int ko = 0; ko < 4; ++ko){
            f32x4 xa = *(const f32x4*)(xp + ko * 32);
            f32x4 xb = *(const f32x4*)(xp + ko * 32 + 4);
            short8 a;
            a[0] = (short)f2bf(xa[0]); a[1] = (short)f2bf(xa[1]);
            a[2] = (short)f2bf(xa[2]); a[3] = (short)f2bf(xa[3]);
            a[4] = (short)f2bf(xb[0]); a[5] = (short)f2bf(xb[1]);
            a[6] = (short)f2bf(xb[2]); a[7] = (short)f2bf(xb[3]);
            short8 b0 = *(const short8*)(w1p + ko * 32);
            short8 b1 = *(const short8*)(w1p + 16 * 128 + ko * 32);
            acc0 = __builtin_amdgcn_mfma_f32_16x16x32_bf16(a, b0, acc0, 0, 0, 0);
            acc1 = __builtin_amdgcn_mfma_f32_16x16x32_bf16(a, b1, acc1, 0, 0, 0);
        }
        #pragma unroll
        for (int nt = 0; nt < 2; ++nt){
            int dl = nt * 16 + m;
            int gc = 8 * dl + jt;             // c2 = 64*dl + 8*jt + w ; gc = c2>>3
            #pragma unroll
            for (int r = 0; r < 4; ++r){
                int t   = q * 4 + r;
                int gcs = gc ^ ((gc >> 3) & 7) ^ (t & 7);
                float v = nt ? acc1[r] : acc0[r];
                s[t * 2048 + gcs * 8 + w] = f2bf(v);
            }
        }
    }
    __syncthreads();

    // ---------- stage 2: 16 k2-blocks, 2 per wave ----------
    f32x4 acc[2][8];
    #pragma unroll
    for (int ki = 0; ki < 2; ++ki)
        #pragma unroll
        for (int nt = 0; nt < 8; ++nt)
            acc[ki][nt] = (f32x4){0.f, 0.f, 0.f, 0.f};

    #pragma unroll
    for (int ki = 0; ki < 2; ++ki){
        int kl = w + (ki << 3);
        const unsigned short* w2p = w2T + ((size_t)((k0 + kl) * 128 + m)) * 128 + q * 8;
        #pragma unroll
        for (int ko = 0; ko < 4; ++ko){
            int gc  = kl * 16 + ko * 4 + q;
            int gcs = gc ^ ((gc >> 3) & 7) ^ (m & 7);
            short8 a = *(const short8*)(s + m * 2048 + gcs * 8);
            #pragma unroll
            for (int nt = 0; nt < 8; ++nt){
                short8 bb = *(const short8*)(w2p + nt * 16 * 128 + ko * 32);
                acc[ki][nt] = __builtin_amdgcn_mfma_f32_16x16x32_bf16(a, bb, acc[ki][nt], 0, 0, 0);
            }
        }
    }
    __syncthreads();

    // ---------- epilogue ----------
    float* osb = (float*)s;
    for (int h = 0; h < 2; ++h){
        if ((q >> 1) == h){
            int tb = (q & 1) * 4;
            #pragma unroll
            for (int ki = 0; ki < 2; ++ki){
                int kl = w + (ki << 3);
                #pragma unroll
                for (int nt = 0; nt < 8; ++nt){
                    int n    = nt * 16 + m;
                    int colc = (n & 63) * 32 + 2 * kl + (n >> 6);
                    int gnum = colc >> 2;
                    #pragma unroll
                    for (int r = 0; r < 4; ++r){
                        int t  = tb + r;
                        int gs = gnum ^ ((gnum >> 3) & 7) ^ (t & 7);
                        osb[t * 2048 + gs * 4 + (colc & 3)] = acc[ki][nt][r];
                    }
                }
            }
        }
        __syncthreads();
        {
            int tr = tid >> 6;            // 0..7
            int cl = tid & 63;            // 0..63
            size_t orow = (size_t)(t0 + 8 * h + tr) * SZ;
            #pragma unroll
            for (int f = 0; f < 8; ++f){
                int colc = cl * 4 + f * 256;
                int gnum = colc >> 2;
                int gs   = gnum ^ ((gnum >> 3) & 7) ^ (tr & 7);
                f32x4 v  = *(const f32x4*)(osb + tr * 2048 + gs * 4);
                int gcol = ((colc >> 5) << 7) + (g << 5) + (colc & 31);
                f32x4 bi = *(const f32x4*)(bias + gcol);
                *(f32x4*)(out + orow + gcol) = v + bi;
            }
        }
        __syncthreads();
    }
}

// ================= fallback: fully fused, no d_ws, per-wave LDS weight transpose =================
__global__ __launch_bounds__(256) void Monarch_fused(const float* __restrict__ x,
                                                     const float* __restrict__ w1,
                                                     const float* __restrict__ w2,
                                                     const float* __restrict__ bias,
                                                     float* __restrict__ out)
{
    __shared__ __align__(16) unsigned short s[16 * 2048];   // 64 KB h2 buffer
    __shared__ __align__(16) unsigned short wst[4 * 5120];  // 40 KB: per-wave transpose scratch

    int b    = blockIdx.x;
    int g    = (b & 7) >> 1;
    int tile = ((b >> 3) << 1) | (b & 1);
    int t0   = tile << 4;
    int k0   = g << 4;
    int d0   = g << 5;

    int tid = threadIdx.x;
    int w   = tid >> 6;
    int l   = tid & 63;
    int m   = l & 15;
    int q   = l >> 4;

    unsigned short* wb = wst + w * 5120;   // wave-private; no barriers needed around it
    int srow = l >> 3;                     // 0..7
    int dcol = (l & 7) * 4;

    // ---------- stage 1 ----------
    const float* xrow = x + (size_t)(t0 + m) * SZ + q * 8;
    for (int jt = 0; jt < 16; ++jt){
        int j = (jt << 2) | w;
        // stage w1 sliver transposed: wb[d'][c] (stride 136) = bf16(w1[j][c][d0+d'])
        const float* wsrc = w1 + (size_t)j * 16384 + d0;
        #pragma unroll
        for (int rr = 0; rr < 16; ++rr){
            int c = rr * 8 + srow;
            f32x4 v = *(const f32x4*)(wsrc + c * 128 + dcol);
            #pragma unroll
            for (int i2 = 0; i2 < 4; ++i2)
                wb[(dcol + i2) * 136 + c] = (unsigned short)(__float_as_uint(v[i2]) >> 16);
        }
        f32x4 acc0 = {0.f, 0.f, 0.f, 0.f};
        f32x4 acc1 = {0.f, 0.f, 0.f, 0.f};
        const float* xp = xrow + j * 128;
        #pragma unroll
        for (int ko = 0; ko < 4; ++ko){
            f32x4 xa = *(const f32x4*)(xp + ko * 32);
            f32x4 xb = *(const f32x4*)(xp + ko * 32 + 4);
            short8 a;
            a[0] = (short)f2bf(xa[0]); a[1] = (short)f2bf(xa[1]);
            a[2] = (short)f2bf(xa[2]); a[3] = (short)f2bf(xa[3]);
            a[4] = (short)f2bf(xb[0]); a[5] = (short)f2bf(xb[1]);
            a[6] = (short)f2bf(xb[2]); a[7] = (short)f2bf(xb[3]);
            short8 b0 = *(const short8*)(wb + m * 136 + ko * 32 + q * 8);
            short8 b1 = *(const short8*)(wb + (m + 16) * 136 + ko * 32 + q * 8);
            acc0 = __builtin_amdgcn_mfma_f32_16x16x32_bf16(a, b0, acc0, 0, 0, 0);
            acc1 = __builtin_amdgcn_mfma_f32_16x16x32_bf16(a, b1, acc1, 0, 0, 0);
        }
        #pragma unroll
        for (int nt = 0; nt < 2; ++nt){
            int dl = nt * 16 + m;
            int gc = 8 * dl + (j >> 3);
            #pragma unroll
            for (int r = 0; r < 4; ++r){
                int t   = q * 4 + r;
                int gcs = gc ^ ((gc >> 3) & 7) ^ (t & 7);
                float v = nt ? acc1[r] : acc0[r];
                s[t * 2048 + gcs * 8 + (j & 7)] = f2bf(v);
            }
        }
    }
    __syncthreads();

    // ---------- stage 2 ----------
    f32x4 acc[4][8];
    #pragma unroll
    for (int ki = 0; ki < 4; ++ki)
        #pragma unroll
        for (int nt = 0; nt < 8; ++nt)
            acc[ki][nt] = (f32x4){0.f, 0.f, 0.f, 0.f};

    for (int ki = 0; ki < 4; ++ki){
        int kl = w + (ki << 2);
        const float* w2src = w2 + (size_t)(k0 + kl) * 16384;
        #pragma unroll
        for (int ko = 0; ko < 4; ++ko){
            // stage chunk transposed: wb[n][cc] (stride 40) = bf16(w2[blk][ko*32+cc][n])
            #pragma unroll
            for (int it = 0; it < 4; ++it){
                int cc = it * 8 + srow;
                const float* rp = w2src + (size_t)(ko * 32 + cc) * 128 + (l & 7) * 16;
                #pragma unroll
                for (int v4 = 0; v4 < 4; ++v4){
                    f32x4 v = *(const f32x4*)(rp + v4 * 4);
                    #pragma unroll
                    for (int i2 = 0; i2 < 4; ++i2)
                        wb[((l & 7) * 16 + v4 * 4 + i2) * 40 + cc] =
                            (unsigned short)(__float_as_uint(v[i2]) >> 16);
                }
            }
            int gc  = kl * 16 + ko * 4 + q;
            int gcs = gc ^ ((gc >> 3) & 7) ^ (m & 7);
            short8 a = *(const short8*)(s + m * 2048 + gcs * 8);
            #pragma unroll
            for (int nt = 0; nt < 8; ++nt){
                short8 bb = *(const short8*)(wb + (nt * 16 + m) * 40 + q * 8);
                acc[ki][nt] = __builtin_amdgcn_mfma_f32_16x16x32_bf16(a, bb, acc[ki][nt], 0, 0, 0);
            }
        }
    }
    __syncthreads();

    // ---------- epilogue (verbatim from validated kernel) ----------
    float* osb = (float*)s;
    for (int h = 0; h < 2; ++h){
        if ((q >> 1) == h){
            int tb = (q & 1) * 4;
            #pragma unroll
            for (int ki = 0; ki < 4; ++ki){
                int kl = w + (ki << 2);
                #pragma unroll
                for (int nt = 0; nt < 8; ++nt){
                    int n    = nt * 16 + m;
                    int colc = (n & 63) * 32 + 2 * kl + (n >> 6);
                    int gnum = colc >> 2;
                    #pragma unroll
                    for (int r = 0; r < 4; ++r){
                        int t  = tb + r;
                        int gs = gnum ^ ((gnum >> 3) & 7) ^ (t & 7);
                        osb[t * 2048 + gs * 4 + (colc & 3)] = acc[ki][nt][r];
                    }
                }
            }
        }
        __syncthreads();
        {
            int tr = tid >> 5;
            int cl = tid & 31;
            size_t orow = (size_t)(t0 + 8 * h + tr) * SZ;
            #pragma unroll
            for (int f = 0; f < 16; ++f){
                int colc = cl * 4 + f * 128;
                int gnum = colc >> 2;
                int gs   = gnum ^ ((gnum >> 3) & 7) ^ (tr & 7);
                f32x4 v  = *(const f32x4*)(osb + tr * 2048 + gs * 4);
                int gcol = ((colc >> 5) << 7) + (g << 5) + (colc & 31);
                f32x4 bi = *(const f32x4*)(bias + gcol);
                *(f32x4*)(out + orow + gcol) = v + bi;
            }
        }
        __syncthreads();
    }
}

extern "C" void kernel_launch(void* const* d_in, const int* in_sizes, int n_in,
                              void* d_out, int out_size, void* d_ws, size_t ws_size,
                              hipStream_t stream) {
    (void)in_sizes; (void)n_in; (void)out_size;
    const float* x    = (const float*)d_in[0];
    const float* w1   = (const float*)d_in[1];
    const float* w2   = (const float*)d_in[2];
    const float* bias = (const float*)d_in[3];

    if (ws_size >= WT_BYTES) {
        // fast path: one-time global weight transpose into workspace
        unsigned short* wt = (unsigned short*)d_ws;
        Monarch_prep<<<dim3(128), dim3(256), 0, stream>>>(w1, w2, wt);
        Monarch_main<<<dim3(1024), dim3(512), 0, stream>>>(x, wt, wt + (size_t)64 * 16384,
                                                           bias, (float*)d_out);
    } else {
        // fallback: fused, workspace-free (per-wave LDS weight transpose)
        Monarch_fused<<<dim3(1024), dim3(256), 0, stream>>>(x, w1, w2, bias, (float*)d_out);
    }
}

// Round 2
// 376.089 us; speedup vs baseline: 1.0006x; 1.0006x over previous
//
#include <hip/hip_runtime.h>

#define SZ 8192
#define WT_BYTES ((size_t)128 * 16384 * 2)   // 4 MB of bf16 transposed weights

typedef short short8 __attribute__((ext_vector_type(8)));
typedef float f32x4 __attribute__((ext_vector_type(4)));

static __device__ __forceinline__ unsigned short f2bf(float f){
    unsigned u = __float_as_uint(f);
    u += 0x7fffu + ((u >> 16) & 1u);          // RNE
    return (unsigned short)(u >> 16);
}

// ================= fast path (needs ws_size >= 4MB) =================
__global__ __launch_bounds__(256) void Monarch_prep(const float* __restrict__ w1,
                                                    const float* __restrict__ w2,
                                                    unsigned short* __restrict__ wt)
{
    __shared__ unsigned short T[128][132];
    int blk = blockIdx.x;
    const float* src = (blk < 64) ? (w1 + (size_t)blk * 16384)
                                  : (w2 + (size_t)(blk - 64) * 16384);
    unsigned short* dst = wt + (size_t)blk * 16384;
    int i  = threadIdx.x;
    int cs = i >> 5;
    int p0 = (i & 31) * 4;
    for (int rr = 0; rr < 16; ++rr){
        int c = rr * 8 + cs;
        f32x4 v = *(const f32x4*)(src + c * 128 + p0);
        T[p0 + 0][c] = f2bf(v[0]);
        T[p0 + 1][c] = f2bf(v[1]);
        T[p0 + 2][c] = f2bf(v[2]);
        T[p0 + 3][c] = f2bf(v[3]);
    }
    __syncthreads();
    for (int rr = 0; rr < 16; ++rr){
        int d = rr * 8 + cs;
        ushort4 o;
        o.x = T[d][p0 + 0]; o.y = T[d][p0 + 1]; o.z = T[d][p0 + 2]; o.w = T[d][p0 + 3];
        *(ushort4*)(dst + d * 128 + p0) = o;
    }
}

// Round-0 structure (256 thr, 252-reg budget for deep load pipelining) +
// XCD-bijective remap (isolated A/B vs round 0: the 4 g-blocks sharing an
// x-tile land on the SAME XCD's L2 -> x HBM fetch ~once).
__global__ __launch_bounds__(256, 2) void Monarch_main(const float* __restrict__ x,
                                                       const unsigned short* __restrict__ w1T,
                                                       const unsigned short* __restrict__ w2T,
                                                       const float* __restrict__ bias,
                                                       float* __restrict__ out)
{
    __shared__ __align__(16) unsigned short s[16 * 2048];

    int b     = blockIdx.x;
    int xcd   = b & 7;            // dispatch round-robins XCDs
    int local = b >> 3;
    int g     = local & 3;        // 4 consecutive locals (same XCD) share one x-tile
    int tile  = (xcd << 5) | (local >> 2);
    int t0    = tile << 4;
    int k0    = g << 4;
    int d0    = g << 5;

    int tid = threadIdx.x;
    int w   = tid >> 6;
    int l   = tid & 63;
    int m   = l & 15;
    int q   = l >> 4;

    const float* xrow = x + (size_t)(t0 + m) * SZ + q * 8;
    for (int jt = 0; jt < 16; ++jt){
        int j = (jt << 2) | w;
        f32x4 acc0 = {0.f, 0.f, 0.f, 0.f};
        f32x4 acc1 = {0.f, 0.f, 0.f, 0.f};
        const float* xp = xrow + j * 128;
        const unsigned short* w1p = w1T + ((size_t)(j * 128 + d0 + m)) * 128 + q * 8;
        #pragma unroll
        for (int ko = 0; ko < 4; ++ko){
            f32x4 xa = *(const f32x4*)(xp + ko * 32);
            f32x4 xb = *(const f32x4*)(xp + ko * 32 + 4);
            short8 a;
            a[0] = (short)f2bf(xa[0]); a[1] = (short)f2bf(xa[1]);
            a[2] = (short)f2bf(xa[2]); a[3] = (short)f2bf(xa[3]);
            a[4] = (short)f2bf(xb[0]); a[5] = (short)f2bf(xb[1]);
            a[6] = (short)f2bf(xb[2]); a[7] = (short)f2bf(xb[3]);
            short8 b0 = *(const short8*)(w1p + ko * 32);
            short8 b1 = *(const short8*)(w1p + 16 * 128 + ko * 32);
            acc0 = __builtin_amdgcn_mfma_f32_16x16x32_bf16(a, b0, acc0, 0, 0, 0);
            acc1 = __builtin_amdgcn_mfma_f32_16x16x32_bf16(a, b1, acc1, 0, 0, 0);
        }
        #pragma unroll
        for (int nt = 0; nt < 2; ++nt){
            int dl = nt * 16 + m;
            int gc = 8 * dl + (j >> 3);
            #pragma unroll
            for (int r = 0; r < 4; ++r){
                int t   = q * 4 + r;
                int gcs = gc ^ ((gc >> 3) & 7) ^ (t & 7);
                float v = nt ? acc1[r] : acc0[r];
                s[t * 2048 + gcs * 8 + (j & 7)] = f2bf(v);
            }
        }
    }
    __syncthreads();

    f32x4 acc[4][8];
    #pragma unroll
    for (int ki = 0; ki < 4; ++ki)
        #pragma unroll
        for (int nt = 0; nt < 8; ++nt)
            acc[ki][nt] = (f32x4){0.f, 0.f, 0.f, 0.f};

    #pragma unroll
    for (int ki = 0; ki < 4; ++ki){
        int kl = w + (ki << 2);
        const unsigned short* w2p = w2T + ((size_t)((k0 + kl) * 128 + m)) * 128 + q * 8;
        #pragma unroll
        for (int ko = 0; ko < 4; ++ko){
            int gc  = kl * 16 + ko * 4 + q;
            int gcs = gc ^ ((gc >> 3) & 7) ^ (m & 7);
            short8 a = *(const short8*)(s + m * 2048 + gcs * 8);
            #pragma unroll
            for (int nt = 0; nt < 8; ++nt){
                short8 bb = *(const short8*)(w2p + nt * 16 * 128 + ko * 32);
                acc[ki][nt] = __builtin_amdgcn_mfma_f32_16x16x32_bf16(a, bb, acc[ki][nt], 0, 0, 0);
            }
        }
    }
    __syncthreads();

    float* osb = (float*)s;
    for (int h = 0; h < 2; ++h){
        if ((q >> 1) == h){
            int tb = (q & 1) * 4;
            #pragma unroll
            for (int ki = 0; ki < 4; ++ki){
                int kl = w + (ki << 2);
                #pragma unroll
                for (int nt = 0; nt < 8; ++nt){
                    int n    = nt * 16 + m;
                    int colc = (n & 63) * 32 + 2 * kl + (n >> 6);
                    int gnum = colc >> 2;
                    #pragma unroll
                    for (int r = 0; r < 4; ++r){
                        int t  = tb + r;
                        int gs = gnum ^ ((gnum >> 3) & 7) ^ (t & 7);
                        osb[t * 2048 + gs * 4 + (colc & 3)] = acc[ki][nt][r];
                    }
                }
            }
        }
        __syncthreads();
        {
            int tr = tid >> 5;
            int cl = tid & 31;
            size_t orow = (size_t)(t0 + 8 * h + tr) * SZ;
            #pragma unroll
            for (int f = 0; f < 16; ++f){
                int colc = cl * 4 + f * 128;
                int gnum = colc >> 2;
                int gs   = gnum ^ ((gnum >> 3) & 7) ^ (tr & 7);
                f32x4 v  = *(const f32x4*)(osb + tr * 2048 + gs * 4);
                int gcol = ((colc >> 5) << 7) + (g << 5) + (colc & 31);
                f32x4 bi = *(const f32x4*)(bias + gcol);
                *(f32x4*)(out + orow + gcol) = v + bi;
            }
        }
        __syncthreads();
    }
}

// ================= fallback: fully fused, no d_ws, per-wave LDS weight transpose =================
__global__ __launch_bounds__(256) void Monarch_fused(const float* __restrict__ x,
                                                     const float* __restrict__ w1,
                                                     const float* __restrict__ w2,
                                                     const float* __restrict__ bias,
                                                     float* __restrict__ out)
{
    __shared__ __align__(16) unsigned short s[16 * 2048];   // 64 KB h2 buffer
    __shared__ __align__(16) unsigned short wst[4 * 5120];  // 40 KB: per-wave transpose scratch

    int b    = blockIdx.x;
    int g    = (b & 7) >> 1;
    int tile = ((b >> 3) << 1) | (b & 1);
    int t0   = tile << 4;
    int k0   = g << 4;
    int d0   = g << 5;

    int tid = threadIdx.x;
    int w   = tid >> 6;
    int l   = tid & 63;
    int m   = l & 15;
    int q   = l >> 4;

    unsigned short* wb = wst + w * 5120;   // wave-private; no barriers needed around it
    int srow = l >> 3;                     // 0..7
    int dcol = (l & 7) * 4;

    // ---------- stage 1 ----------
    const float* xrow = x + (size_t)(t0 + m) * SZ + q * 8;
    for (int jt = 0; jt < 16; ++jt){
        int j = (jt << 2) | w;
        // stage w1 sliver transposed: wb[d'][c] (stride 136) = bf16(w1[j][c][d0+d'])
        const float* wsrc = w1 + (size_t)j * 16384 + d0;
        #pragma unroll
        for (int rr = 0; rr < 16; ++rr){
            int c = rr * 8 + srow;
            f32x4 v = *(const f32x4*)(wsrc + c * 128 + dcol);
            #pragma unroll
            for (int i2 = 0; i2 < 4; ++i2)
                wb[(dcol + i2) * 136 + c] = (unsigned short)(__float_as_uint(v[i2]) >> 16);
        }
        f32x4 acc0 = {0.f, 0.f, 0.f, 0.f};
        f32x4 acc1 = {0.f, 0.f, 0.f, 0.f};
        const float* xp = xrow + j * 128;
        #pragma unroll
        for (int ko = 0; ko < 4; ++ko){
            f32x4 xa = *(const f32x4*)(xp + ko * 32);
            f32x4 xb = *(const f32x4*)(xp + ko * 32 + 4);
            short8 a;
            a[0] = (short)f2bf(xa[0]); a[1] = (short)f2bf(xa[1]);
            a[2] = (short)f2bf(xa[2]); a[3] = (short)f2bf(xa[3]);
            a[4] = (short)f2bf(xb[0]); a[5] = (short)f2bf(xb[1]);
            a[6] = (short)f2bf(xb[2]); a[7] = (short)f2bf(xb[3]);
            short8 b0 = *(const short8*)(wb + m * 136 + ko * 32 + q * 8);
            short8 b1 = *(const short8*)(wb + (m + 16) * 136 + ko * 32 + q * 8);
            acc0 = __builtin_amdgcn_mfma_f32_16x16x32_bf16(a, b0, acc0, 0, 0, 0);
            acc1 = __builtin_amdgcn_mfma_f32_16x16x32_bf16(a, b1, acc1, 0, 0, 0);
        }
        #pragma unroll
        for (int nt = 0; nt < 2; ++nt){
            int dl = nt * 16 + m;
            int gc = 8 * dl + (j >> 3);
            #pragma unroll
            for (int r = 0; r < 4; ++r){
                int t   = q * 4 + r;
                int gcs = gc ^ ((gc >> 3) & 7) ^ (t & 7);
                float v = nt ? acc1[r] : acc0[r];
                s[t * 2048 + gcs * 8 + (j & 7)] = f2bf(v);
            }
        }
    }
    __syncthreads();

    // ---------- stage 2 ----------
    f32x4 acc[4][8];
    #pragma unroll
    for (int ki = 0; ki < 4; ++ki)
        #pragma unroll
        for (int nt = 0; nt < 8; ++nt)
            acc[ki][nt] = (f32x4){0.f, 0.f, 0.f, 0.f};

    for (int ki = 0; ki < 4; ++ki){
        int kl = w + (ki << 2);
        const float* w2src = w2 + (size_t)(k0 + kl) * 16384;
        #pragma unroll
        for (int ko = 0; ko < 4; ++ko){
            // stage chunk transposed: wb[n][cc] (stride 40) = bf16(w2[blk][ko*32+cc][n])
            #pragma unroll
            for (int it = 0; it < 4; ++it){
                int cc = it * 8 + srow;
                const float* rp = w2src + (size_t)(ko * 32 + cc) * 128 + (l & 7) * 16;
                #pragma unroll
                for (int v4 = 0; v4 < 4; ++v4){
                    f32x4 v = *(const f32x4*)(rp + v4 * 4);
                    #pragma unroll
                    for (int i2 = 0; i2 < 4; ++i2)
                        wb[((l & 7) * 16 + v4 * 4 + i2) * 40 + cc] =
                            (unsigned short)(__float_as_uint(v[i2]) >> 16);
                }
            }
            int gc  = kl * 16 + ko * 4 + q;
            int gcs = gc ^ ((gc >> 3) & 7) ^ (m & 7);
            short8 a = *(const short8*)(s + m * 2048 + gcs * 8);
            #pragma unroll
            for (int nt = 0; nt < 8; ++nt){
                short8 bb = *(const short8*)(wb + (nt * 16 + m) * 40 + q * 8);
                acc[ki][nt] = __builtin_amdgcn_mfma_f32_16x16x32_bf16(a, bb, acc[ki][nt], 0, 0, 0);
            }
        }
    }
    __syncthreads();

    // ---------- epilogue (verbatim from validated kernel) ----------
    float* osb = (float*)s;
    for (int h = 0; h < 2; ++h){
        if ((q >> 1) == h){
            int tb = (q & 1) * 4;
            #pragma unroll
            for (int ki = 0; ki < 4; ++ki){
                int kl = w + (ki << 2);
                #pragma unroll
                for (int nt = 0; nt < 8; ++nt){
                    int n    = nt * 16 + m;
                    int colc = (n & 63) * 32 + 2 * kl + (n >> 6);
                    int gnum = colc >> 2;
                    #pragma unroll
                    for (int r = 0; r < 4; ++r){
                        int t  = tb + r;
                        int gs = gnum ^ ((gnum >> 3) & 7) ^ (t & 7);
                        osb[t * 2048 + gs * 4 + (colc & 3)] = acc[ki][nt][r];
                    }
                }
            }
        }
        __syncthreads();
        {
            int tr = tid >> 5;
            int cl = tid & 31;
            size_t orow = (size_t)(t0 + 8 * h + tr) * SZ;
            #pragma unroll
            for (int f = 0; f < 16; ++f){
                int colc = cl * 4 + f * 128;
                int gnum = colc >> 2;
                int gs   = gnum ^ ((gnum >> 3) & 7) ^ (tr & 7);
                f32x4 v  = *(const f32x4*)(osb + tr * 2048 + gs * 4);
                int gcol = ((colc >> 5) << 7) + (g << 5) + (colc & 31);
                f32x4 bi = *(const f32x4*)(bias + gcol);
                *(f32x4*)(out + orow + gcol) = v + bi;
            }
        }
        __syncthreads();
    }
}

extern "C" void kernel_launch(void* const* d_in, const int* in_sizes, int n_in,
                              void* d_out, int out_size, void* d_ws, size_t ws_size,
                              hipStream_t stream) {
    (void)in_sizes; (void)n_in; (void)out_size;
    const float* x    = (const float*)d_in[0];
    const float* w1   = (const float*)d_in[1];
    const float* w2   = (const float*)d_in[2];
    const float* bias = (const float*)d_in[3];

    if (ws_size >= WT_BYTES) {
        // fast path: one-time global weight transpose into workspace
        unsigned short* wt = (unsigned short*)d_ws;
        Monarch_prep<<<dim3(128), dim3(256), 0, stream>>>(w1, w2, wt);
        Monarch_main<<<dim3(1024), dim3(256), 0, stream>>>(x, wt, wt + (size_t)64 * 16384,
                                                           bias, (float*)d_out);
    } else {
        // fallback: fused, workspace-free (per-wave LDS weight transpose)
        Monarch_fused<<<dim3(1024), dim3(256), 0, stream>>>(x, w1, w2, bias, (float*)d_out);
    }
}

// Round 3
// 321.603 us; speedup vs baseline: 1.1701x; 1.1694x over previous
//
#include <hip/hip_runtime.h>

#define SZ 8192
#define WT_BYTES ((size_t)128 * 16384 * 2)   // 4 MB of bf16 transposed weights

typedef short short8 __attribute__((ext_vector_type(8)));
typedef float f32x4 __attribute__((ext_vector_type(4)));

static __device__ __forceinline__ unsigned short f2bf(float f){
    unsigned u = __float_as_uint(f);
    u += 0x7fffu + ((u >> 16) & 1u);          // RNE
    return (unsigned short)(u >> 16);
}

// ================= fast path (needs ws_size >= 4MB) =================
__global__ __launch_bounds__(256) void Monarch_prep(const float* __restrict__ w1,
                                                    const float* __restrict__ w2,
                                                    unsigned short* __restrict__ wt)
{
    __shared__ unsigned short T[128][132];
    int blk = blockIdx.x;
    const float* src = (blk < 64) ? (w1 + (size_t)blk * 16384)
                                  : (w2 + (size_t)(blk - 64) * 16384);
    unsigned short* dst = wt + (size_t)blk * 16384;
    int i  = threadIdx.x;
    int cs = i >> 5;
    int p0 = (i & 31) * 4;
    for (int rr = 0; rr < 16; ++rr){
        int c = rr * 8 + cs;
        f32x4 v = *(const f32x4*)(src + c * 128 + p0);
        T[p0 + 0][c] = f2bf(v[0]);
        T[p0 + 1][c] = f2bf(v[1]);
        T[p0 + 2][c] = f2bf(v[2]);
        T[p0 + 3][c] = f2bf(v[3]);
    }
    __syncthreads();
    for (int rr = 0; rr < 16; ++rr){
        int d = rr * 8 + cs;
        ushort4 o;
        o.x = T[d][p0 + 0]; o.y = T[d][p0 + 1]; o.z = T[d][p0 + 2]; o.w = T[d][p0 + 3];
        *(ushort4*)(dst + d * 128 + p0) = o;
    }
}

// 32-token blocks: each weight fragment feeds TWO token tiles (2 MFMAs/load in
// stage 2), halving per-token weight traffic and per-wave VMEM count.
// 512 thr, 1 block/CU (128 KB LDS), 2 waves/SIMD -> 256-reg budget/wave.
__global__ __launch_bounds__(512, 2) void Monarch_main(const float* __restrict__ x,
                                                       const unsigned short* __restrict__ w1T,
                                                       const unsigned short* __restrict__ w2T,
                                                       const float* __restrict__ bias,
                                                       float* __restrict__ out)
{
    __shared__ __align__(16) unsigned short s[32 * 2048];   // 128 KB h1 buffer (32 tokens)

    int b     = blockIdx.x;          // 512 blocks
    int xcd   = b & 7;
    int local = b >> 3;              // 0..63
    int g     = local & 3;           // 4 consecutive locals (same XCD) share one token group
    int tgrp  = (xcd << 4) | (local >> 2);   // 0..127
    int t0    = tgrp << 5;           // 32 tokens per block
    int k0    = g << 4;
    int d0    = g << 5;

    int tid = threadIdx.x;
    int w   = tid >> 6;              // 0..7
    int l   = tid & 63;
    int m   = l & 15;
    int q   = l >> 4;

    // ---------- stage 1: h1 slice [32 tok x 32 d' x 64 j] ----------
    const float* xrow0 = x + (size_t)(t0 + m) * SZ + q * 8;
    const float* xrow1 = xrow0 + (size_t)16 * SZ;
    for (int jt = 0; jt < 8; ++jt){
        int j = (jt << 3) | w;
        f32x4 acc00 = {0.f,0.f,0.f,0.f}, acc01 = {0.f,0.f,0.f,0.f};  // tile0: d-half 0/1
        f32x4 acc10 = {0.f,0.f,0.f,0.f}, acc11 = {0.f,0.f,0.f,0.f};  // tile1
        const float* xp0 = xrow0 + j * 128;
        const float* xp1 = xrow1 + j * 128;
        const unsigned short* w1p = w1T + ((size_t)(j * 128 + d0 + m)) * 128 + q * 8;
        #pragma unroll
        for (int ko = 0; ko < 4; ++ko){
            short8 b0 = *(const short8*)(w1p + ko * 32);
            short8 b1 = *(const short8*)(w1p + 16 * 128 + ko * 32);
            f32x4 xa0 = *(const f32x4*)(xp0 + ko * 32);
            f32x4 xb0 = *(const f32x4*)(xp0 + ko * 32 + 4);
            f32x4 xa1 = *(const f32x4*)(xp1 + ko * 32);
            f32x4 xb1 = *(const f32x4*)(xp1 + ko * 32 + 4);
            short8 a0, a1;
            a0[0] = (short)f2bf(xa0[0]); a0[1] = (short)f2bf(xa0[1]);
            a0[2] = (short)f2bf(xa0[2]); a0[3] = (short)f2bf(xa0[3]);
            a0[4] = (short)f2bf(xb0[0]); a0[5] = (short)f2bf(xb0[1]);
            a0[6] = (short)f2bf(xb0[2]); a0[7] = (short)f2bf(xb0[3]);
            a1[0] = (short)f2bf(xa1[0]); a1[1] = (short)f2bf(xa1[1]);
            a1[2] = (short)f2bf(xa1[2]); a1[3] = (short)f2bf(xa1[3]);
            a1[4] = (short)f2bf(xb1[0]); a1[5] = (short)f2bf(xb1[1]);
            a1[6] = (short)f2bf(xb1[2]); a1[7] = (short)f2bf(xb1[3]);
            acc00 = __builtin_amdgcn_mfma_f32_16x16x32_bf16(a0, b0, acc00, 0, 0, 0);
            acc01 = __builtin_amdgcn_mfma_f32_16x16x32_bf16(a0, b1, acc01, 0, 0, 0);
            acc10 = __builtin_amdgcn_mfma_f32_16x16x32_bf16(a1, b0, acc10, 0, 0, 0);
            acc11 = __builtin_amdgcn_mfma_f32_16x16x32_bf16(a1, b1, acc11, 0, 0, 0);
        }
        #pragma unroll
        for (int r = 0; r < 4; ++r){
            int t   = q * 4 + r;
            int gc0 = 8 * m + jt;                 // d-half 0: dl = m
            int gc1 = 8 * (16 + m) + jt;          // d-half 1: dl = 16+m
            int gcs0 = gc0 ^ ((gc0 >> 3) & 7) ^ (t & 7);
            int gcs1 = gc1 ^ ((gc1 >> 3) & 7) ^ (t & 7);
            s[t * 2048 + gcs0 * 8 + w]        = f2bf(acc00[r]);
            s[t * 2048 + gcs1 * 8 + w]        = f2bf(acc01[r]);
            s[(t + 16) * 2048 + gcs0 * 8 + w] = f2bf(acc10[r]);
            s[(t + 16) * 2048 + gcs1 * 8 + w] = f2bf(acc11[r]);
        }
    }
    __syncthreads();

    // ---------- stage 2: 16 k2-blocks, 2 per wave, each bb feeds 2 tiles ----------
    f32x4 acc[2][2][8];   // [ki][u][nt]
    #pragma unroll
    for (int ki = 0; ki < 2; ++ki)
        #pragma unroll
        for (int u = 0; u < 2; ++u)
            #pragma unroll
            for (int nt = 0; nt < 8; ++nt)
                acc[ki][u][nt] = (f32x4){0.f, 0.f, 0.f, 0.f};

    #pragma unroll
    for (int ki = 0; ki < 2; ++ki){
        int kl = w + (ki << 3);
        const unsigned short* w2p = w2T + ((size_t)((k0 + kl) * 128 + m)) * 128 + q * 8;
        #pragma unroll
        for (int ko = 0; ko < 4; ++ko){
            int gc  = kl * 16 + ko * 4 + q;
            int gcs = gc ^ ((gc >> 3) & 7) ^ (m & 7);
            short8 a0 = *(const short8*)(s + m * 2048 + gcs * 8);
            short8 a1 = *(const short8*)(s + (m + 16) * 2048 + gcs * 8);
            #pragma unroll
            for (int nt = 0; nt < 8; ++nt){
                short8 bb = *(const short8*)(w2p + nt * 16 * 128 + ko * 32);
                acc[ki][0][nt] = __builtin_amdgcn_mfma_f32_16x16x32_bf16(a0, bb, acc[ki][0][nt], 0, 0, 0);
                acc[ki][1][nt] = __builtin_amdgcn_mfma_f32_16x16x32_bf16(a1, bb, acc[ki][1][nt], 0, 0, 0);
            }
        }
    }
    __syncthreads();

    // ---------- epilogue: 4 half-tiles of 8 token rows ----------
    float* osb = (float*)s;
    #pragma unroll
    for (int u = 0; u < 2; ++u){
        #pragma unroll
        for (int h = 0; h < 2; ++h){
            if ((q >> 1) == h){
                int tb = (q & 1) * 4;
                #pragma unroll
                for (int ki = 0; ki < 2; ++ki){
                    int kl = w + (ki << 3);
                    #pragma unroll
                    for (int nt = 0; nt < 8; ++nt){
                        int n    = nt * 16 + m;
                        int colc = (n & 63) * 32 + 2 * kl + (n >> 6);
                        int gnum = colc >> 2;
                        #pragma unroll
                        for (int r = 0; r < 4; ++r){
                            int t  = tb + r;
                            int gs = gnum ^ ((gnum >> 3) & 7) ^ (t & 7);
                            osb[t * 2048 + gs * 4 + (colc & 3)] = acc[ki][u][nt][r];
                        }
                    }
                }
            }
            __syncthreads();
            {
                int tr = tid >> 6;            // 0..7
                int cl = tid & 63;            // 0..63
                size_t orow = (size_t)(t0 + u * 16 + 8 * h + tr) * SZ;
                #pragma unroll
                for (int f = 0; f < 8; ++f){
                    int colc = cl * 4 + f * 256;
                    int gnum = colc >> 2;
                    int gs   = gnum ^ ((gnum >> 3) & 7) ^ (tr & 7);
                    f32x4 v  = *(const f32x4*)(osb + tr * 2048 + gs * 4);
                    int gcol = ((colc >> 5) << 7) + (g << 5) + (colc & 31);
                    f32x4 bi = *(const f32x4*)(bias + gcol);
                    *(f32x4*)(out + orow + gcol) = v + bi;
                }
            }
            __syncthreads();
        }
    }
}

// ================= fallback: fully fused, no d_ws, per-wave LDS weight transpose =================
__global__ __launch_bounds__(256) void Monarch_fused(const float* __restrict__ x,
                                                     const float* __restrict__ w1,
                                                     const float* __restrict__ w2,
                                                     const float* __restrict__ bias,
                                                     float* __restrict__ out)
{
    __shared__ __align__(16) unsigned short s[16 * 2048];   // 64 KB h2 buffer
    __shared__ __align__(16) unsigned short wst[4 * 5120];  // 40 KB: per-wave transpose scratch

    int b    = blockIdx.x;
    int g    = (b & 7) >> 1;
    int tile = ((b >> 3) << 1) | (b & 1);
    int t0   = tile << 4;
    int k0   = g << 4;
    int d0   = g << 5;

    int tid = threadIdx.x;
    int w   = tid >> 6;
    int l   = tid & 63;
    int m   = l & 15;
    int q   = l >> 4;

    unsigned short* wb = wst + w * 5120;   // wave-private; no barriers needed around it
    int srow = l >> 3;                     // 0..7
    int dcol = (l & 7) * 4;

    // ---------- stage 1 ----------
    const float* xrow = x + (size_t)(t0 + m) * SZ + q * 8;
    for (int jt = 0; jt < 16; ++jt){
        int j = (jt << 2) | w;
        const float* wsrc = w1 + (size_t)j * 16384 + d0;
        #pragma unroll
        for (int rr = 0; rr < 16; ++rr){
            int c = rr * 8 + srow;
            f32x4 v = *(const f32x4*)(wsrc + c * 128 + dcol);
            #pragma unroll
            for (int i2 = 0; i2 < 4; ++i2)
                wb[(dcol + i2) * 136 + c] = (unsigned short)(__float_as_uint(v[i2]) >> 16);
        }
        f32x4 acc0 = {0.f, 0.f, 0.f, 0.f};
        f32x4 acc1 = {0.f, 0.f, 0.f, 0.f};
        const float* xp = xrow + j * 128;
        #pragma unroll
        for (int ko = 0; ko < 4; ++ko){
            f32x4 xa = *(const f32x4*)(xp + ko * 32);
            f32x4 xb = *(const f32x4*)(xp + ko * 32 + 4);
            short8 a;
            a[0] = (short)f2bf(xa[0]); a[1] = (short)f2bf(xa[1]);
            a[2] = (short)f2bf(xa[2]); a[3] = (short)f2bf(xa[3]);
            a[4] = (short)f2bf(xb[0]); a[5] = (short)f2bf(xb[1]);
            a[6] = (short)f2bf(xb[2]); a[7] = (short)f2bf(xb[3]);
            short8 b0 = *(const short8*)(wb + m * 136 + ko * 32 + q * 8);
            short8 b1 = *(const short8*)(wb + (m + 16) * 136 + ko * 32 + q * 8);
            acc0 = __builtin_amdgcn_mfma_f32_16x16x32_bf16(a, b0, acc0, 0, 0, 0);
            acc1 = __builtin_amdgcn_mfma_f32_16x16x32_bf16(a, b1, acc1, 0, 0, 0);
        }
        #pragma unroll
        for (int nt = 0; nt < 2; ++nt){
            int dl = nt * 16 + m;
            int gc = 8 * dl + (j >> 3);
            #pragma unroll
            for (int r = 0; r < 4; ++r){
                int t   = q * 4 + r;
                int gcs = gc ^ ((gc >> 3) & 7) ^ (t & 7);
                float v = nt ? acc1[r] : acc0[r];
                s[t * 2048 + gcs * 8 + (j & 7)] = f2bf(v);
            }
        }
    }
    __syncthreads();

    // ---------- stage 2 ----------
    f32x4 acc[4][8];
    #pragma unroll
    for (int ki = 0; ki < 4; ++ki)
        #pragma unroll
        for (int nt = 0; nt < 8; ++nt)
            acc[ki][nt] = (f32x4){0.f, 0.f, 0.f, 0.f};

    for (int ki = 0; ki < 4; ++ki){
        int kl = w + (ki << 2);
        const float* w2src = w2 + (size_t)(k0 + kl) * 16384;
        #pragma unroll
        for (int ko = 0; ko < 4; ++ko){
            #pragma unroll
            for (int it = 0; it < 4; ++it){
                int cc = it * 8 + srow;
                const float* rp = w2src + (size_t)(ko * 32 + cc) * 128 + (l & 7) * 16;
                #pragma unroll
                for (int v4 = 0; v4 < 4; ++v4){
                    f32x4 v = *(const f32x4*)(rp + v4 * 4);
                    #pragma unroll
                    for (int i2 = 0; i2 < 4; ++i2)
                        wb[((l & 7) * 16 + v4 * 4 + i2) * 40 + cc] =
                            (unsigned short)(__float_as_uint(v[i2]) >> 16);
                }
            }
            int gc  = kl * 16 + ko * 4 + q;
            int gcs = gc ^ ((gc >> 3) & 7) ^ (m & 7);
            short8 a = *(const short8*)(s + m * 2048 + gcs * 8);
            #pragma unroll
            for (int nt = 0; nt < 8; ++nt){
                short8 bb = *(const short8*)(wb + (nt * 16 + m) * 40 + q * 8);
                acc[ki][nt] = __builtin_amdgcn_mfma_f32_16x16x32_bf16(a, bb, acc[ki][nt], 0, 0, 0);
            }
        }
    }
    __syncthreads();

    // ---------- epilogue ----------
    float* osb = (float*)s;
    for (int h = 0; h < 2; ++h){
        if ((q >> 1) == h){
            int tb = (q & 1) * 4;
            #pragma unroll
            for (int ki = 0; ki < 4; ++ki){
                int kl = w + (ki << 2);
                #pragma unroll
                for (int nt = 0; nt < 8; ++nt){
                    int n    = nt * 16 + m;
                    int colc = (n & 63) * 32 + 2 * kl + (n >> 6);
                    int gnum = colc >> 2;
                    #pragma unroll
                    for (int r = 0; r < 4; ++r){
                        int t  = tb + r;
                        int gs = gnum ^ ((gnum >> 3) & 7) ^ (t & 7);
                        osb[t * 2048 + gs * 4 + (colc & 3)] = acc[ki][nt][r];
                    }
                }
            }
        }
        __syncthreads();
        {
            int tr = tid >> 5;
            int cl = tid & 31;
            size_t orow = (size_t)(t0 + 8 * h + tr) * SZ;
            #pragma unroll
            for (int f = 0; f < 16; ++f){
                int colc = cl * 4 + f * 128;
                int gnum = colc >> 2;
                int gs   = gnum ^ ((gnum >> 3) & 7) ^ (tr & 7);
                f32x4 v  = *(const f32x4*)(osb + tr * 2048 + gs * 4);
                int gcol = ((colc >> 5) << 7) + (g << 5) + (colc & 31);
                f32x4 bi = *(const f32x4*)(bias + gcol);
                *(f32x4*)(out + orow + gcol) = v + bi;
            }
        }
        __syncthreads();
    }
}

extern "C" void kernel_launch(void* const* d_in, const int* in_sizes, int n_in,
                              void* d_out, int out_size, void* d_ws, size_t ws_size,
                              hipStream_t stream) {
    (void)in_sizes; (void)n_in; (void)out_size;
    const float* x    = (const float*)d_in[0];
    const float* w1   = (const float*)d_in[1];
    const float* w2   = (const float*)d_in[2];
    const float* bias = (const float*)d_in[3];

    if (ws_size >= WT_BYTES) {
        // fast path: one-time global weight transpose into workspace
        unsigned short* wt = (unsigned short*)d_ws;
        Monarch_prep<<<dim3(128), dim3(256), 0, stream>>>(w1, w2, wt);
        Monarch_main<<<dim3(512), dim3(512), 0, stream>>>(x, wt, wt + (size_t)64 * 16384,
                                                          bias, (float*)d_out);
    } else {
        // fallback: fused, workspace-free (per-wave LDS weight transpose)
        Monarch_fused<<<dim3(1024), dim3(256), 0, stream>>>(x, w1, w2, bias, (float*)d_out);
    }
}